// Round 2
// baseline (441.082 us; speedup 1.0000x reference)
//
#include <hip/hip_runtime.h>

typedef __bf16 bf16;
typedef bf16 bf16x4 __attribute__((ext_vector_type(4)));
typedef bf16 bf16x8 __attribute__((ext_vector_type(8)));
typedef float f32x4 __attribute__((ext_vector_type(4)));

// ws element offsets (bf16 elements)
#define WS_WREL_T  0
#define WS_WNODE_T 16384
#define WS_W1T     32768
#define WS_W2T     98304
#define WS_QG      163840

// ---------- prep: transpose weights to B^T (N-major) bf16 ----------
__global__ void prep_weights(const float* __restrict__ Wrel,
                             const float* __restrict__ Wnode,
                             const float* __restrict__ W1,
                             const float* __restrict__ W2,
                             bf16* __restrict__ ws) {
  int id = blockIdx.x * 256 + threadIdx.x;
  if (id < 16384) {
    ws[WS_WREL_T + id] = (bf16)Wrel[(id & 127) * 128 + (id >> 7)];
  } else if (id < 32768) {
    int j = id - 16384;
    ws[WS_WNODE_T + j] = (bf16)Wnode[(j & 127) * 128 + (j >> 7)];
  } else if (id < 98304) {
    int j = id - 32768;
    ws[WS_W1T + j] = (bf16)W1[(j & 255) * 256 + (j >> 8)];
  } else if (id < 163840) {
    int j = id - 98304;
    ws[WS_W2T + j] = (bf16)W2[(j & 255) * 256 + (j >> 8)];
  }
}

// ---------- prep: qg[64][256] = sigmoid(question @ W_qgate), bf16 ----------
__global__ void prep_qg(const float* __restrict__ question,
                        const float* __restrict__ Wq,
                        bf16* __restrict__ ws) {
  int b = blockIdx.x, c = threadIdx.x;
  float s = 0.f;
#pragma unroll 8
  for (int k = 0; k < 128; ++k) s += question[b * 128 + k] * Wq[k * 256 + c];
  ws[WS_QG + b * 256 + c] = (bf16)(1.f / (1.f + expf(-s)));
}

__device__ __forceinline__ float gelu_erf(float x) {
  return 0.5f * x * (1.f + erff(x * 0.70710678118654752f));
}

// ---------- main fused kernel: 64 edges/block, 4 waves, 32KB union LDS ----------
__global__ __launch_bounds__(256, 4) void fused_main(
    const float* __restrict__ rel_tok,   // [E,128]
    const float* __restrict__ node_tok,  // [N,128]
    const int*   __restrict__ tail_idx,  // edge_index + E
    const int*   __restrict__ ebatch,    // [E]
    const bf16*  __restrict__ Wrel_t,    // [128][128] (B^T)
    const bf16*  __restrict__ Wnode_t,   // [128][128]
    const bf16*  __restrict__ W1t,       // [256][256]
    const bf16*  __restrict__ W2t,       // [256][256]
    const bf16*  __restrict__ qg,        // [64][256]
    const float* __restrict__ b1,
    const float* __restrict__ b2,
    float* __restrict__ out)             // [E,256]
{
  // One 32KB union buffer, three phase layouts:
  //  T : tokens  [2][64][128] bf16, byte off = h*16384 + row*256 + ((col*2)^((row&7)<<4))
  //  AK: act-key [64][256]    bf16, byte off = row*512 + ((col*2)^((row&7)<<4))
  //  H : hidden  same as AK
  __shared__ char s_buf[64 * 256 * 2];
  __shared__ int  s_eb[64];

  const int tid = threadIdx.x;
  const int w = tid >> 6;
  const int l = tid & 63;
  const int lo = l & 15;
  const int hi = l >> 4;
  const int base = blockIdx.x * 64;

  if (tid < 64) s_eb[tid] = ebatch[base + tid];

  // ---- stage tokens -> LDS bf16 (phase T) ----
  {
    const float4* g = (const float4*)rel_tok + (size_t)base * 32;
#pragma unroll
    for (int i = 0; i < 8; ++i) {
      int idx = tid + i * 256;          // over [64][32] float4
      int row = idx >> 5, c4 = idx & 31;
      float4 v = g[idx];
      bf16x4 b; b[0] = (bf16)v.x; b[1] = (bf16)v.y; b[2] = (bf16)v.z; b[3] = (bf16)v.w;
      int off = row * 256 + ((c4 * 8) ^ ((row & 7) << 4));
      *(bf16x4*)(s_buf + off) = b;
    }
#pragma unroll
    for (int i = 0; i < 8; ++i) {
      int idx = tid + i * 256;
      int row = idx >> 5, c4 = idx & 31;
      int tail = tail_idx[base + row];  // 32 lanes same addr: coalesces
      float4 v = ((const float4*)node_tok)[(size_t)tail * 32 + c4];
      bf16x4 b; b[0] = (bf16)v.x; b[1] = (bf16)v.y; b[2] = (bf16)v.z; b[3] = (bf16)v.w;
      int off = 16384 + row * 256 + ((c4 * 8) ^ ((row & 7) << 4));
      *(bf16x4*)(s_buf + off) = b;
    }
  }
  __syncthreads();   // (1) tokens + s_eb visible

  const f32x4 zero4 = {0.f, 0.f, 0.f, 0.f};

  // ---- stage 1: rel_key / node_key (K=128), gate -> packed regs ----
  bf16x4 pak[2][4][2];   // [h][ri][ci], 4 rows each = 64 bf16 = 32 VGPR
#pragma unroll
  for (int h = 0; h < 2; ++h) {
    const bf16* Wt = h ? Wnode_t : Wrel_t;
    f32x4 acc[4][2];
#pragma unroll
    for (int ri = 0; ri < 4; ++ri)
#pragma unroll
      for (int ci = 0; ci < 2; ++ci) acc[ri][ci] = zero4;

#pragma unroll
    for (int kk = 0; kk < 4; ++kk) {
      bf16x8 a[4], b[2];
#pragma unroll
      for (int ri = 0; ri < 4; ++ri) {
        int row = ri * 16 + lo;
        int off = h * 16384 + row * 256 + ((((kk * 4 + hi) * 16)) ^ ((row & 7) << 4));
        a[ri] = *(const bf16x8*)(s_buf + off);
      }
#pragma unroll
      for (int ci = 0; ci < 2; ++ci) {
        int n = w * 32 + ci * 16 + lo;
        b[ci] = *(const bf16x8*)(Wt + n * 128 + kk * 32 + hi * 8);
      }
#pragma unroll
      for (int ri = 0; ri < 4; ++ri)
#pragma unroll
        for (int ci = 0; ci < 2; ++ci)
          acc[ri][ci] = __builtin_amdgcn_mfma_f32_16x16x32_bf16(a[ri], b[ci], acc[ri][ci], 0, 0, 0);
    }
    // gate multiply into packed bf16 regs (no LDS write yet)
#pragma unroll
    for (int ri = 0; ri < 4; ++ri)
#pragma unroll
      for (int ci = 0; ci < 2; ++ci)
#pragma unroll
        for (int r = 0; r < 4; ++r) {
          int row = ri * 16 + hi * 4 + r;
          int col = h * 128 + w * 32 + ci * 16 + lo;
          float gv = (float)qg[s_eb[row] * 256 + col];
          pak[h][ri][ci][r] = (bf16)(acc[ri][ci][r] * gv);
        }
  }
  __syncthreads();   // (2) all waves done READING token phase

  // write action_key over the token buffer (phase AK)
#pragma unroll
  for (int h = 0; h < 2; ++h)
#pragma unroll
    for (int ri = 0; ri < 4; ++ri)
#pragma unroll
      for (int ci = 0; ci < 2; ++ci)
#pragma unroll
        for (int r = 0; r < 4; ++r) {
          int row = ri * 16 + hi * 4 + r;
          int col = h * 128 + w * 32 + ci * 16 + lo;
          int off = row * 512 + ((col * 2) ^ ((row & 7) << 4));
          *(bf16*)(s_buf + off) = pak[h][ri][ci][r];
        }
  __syncthreads();   // (3) AK visible

  // ---- stage 2: h = gelu(ak @ W1^T + b1) ----
  {
    f32x4 acc[4][4];
#pragma unroll
    for (int ri = 0; ri < 4; ++ri)
#pragma unroll
      for (int ci = 0; ci < 4; ++ci) acc[ri][ci] = zero4;

#pragma unroll
    for (int kk = 0; kk < 8; ++kk) {
      bf16x8 a[4], b[4];
#pragma unroll
      for (int ri = 0; ri < 4; ++ri) {
        int row = ri * 16 + lo;
        int off = row * 512 + ((((kk * 4 + hi) * 16)) ^ ((row & 7) << 4));
        a[ri] = *(const bf16x8*)(s_buf + off);
      }
#pragma unroll
      for (int ci = 0; ci < 4; ++ci) {
        int n = w * 64 + ci * 16 + lo;
        b[ci] = *(const bf16x8*)(W1t + n * 256 + kk * 32 + hi * 8);
      }
#pragma unroll
      for (int ri = 0; ri < 4; ++ri)
#pragma unroll
        for (int ci = 0; ci < 4; ++ci)
          acc[ri][ci] = __builtin_amdgcn_mfma_f32_16x16x32_bf16(a[ri], b[ci], acc[ri][ci], 0, 0, 0);
    }
    __syncthreads();   // (4) all waves done READING AK
    float b1v[4];
#pragma unroll
    for (int ci = 0; ci < 4; ++ci) b1v[ci] = b1[w * 64 + ci * 16 + lo];
#pragma unroll
    for (int ri = 0; ri < 4; ++ri)
#pragma unroll
      for (int ci = 0; ci < 4; ++ci)
#pragma unroll
        for (int r = 0; r < 4; ++r) {
          int row = ri * 16 + hi * 4 + r;
          int col = w * 64 + ci * 16 + lo;
          float v = gelu_erf(acc[ri][ci][r] + b1v[ci]);
          int off = row * 512 + ((col * 2) ^ ((row & 7) << 4));
          *(bf16*)(s_buf + off) = (bf16)v;
        }
  }
  __syncthreads();   // (5) H visible

  // ---- stage 3: out = h @ W2^T + b2 -> global fp32 ----
  {
    f32x4 acc[4][4];
#pragma unroll
    for (int ri = 0; ri < 4; ++ri)
#pragma unroll
      for (int ci = 0; ci < 4; ++ci) acc[ri][ci] = zero4;

#pragma unroll
    for (int kk = 0; kk < 8; ++kk) {
      bf16x8 a[4], b[4];
#pragma unroll
      for (int ri = 0; ri < 4; ++ri) {
        int row = ri * 16 + lo;
        int off = row * 512 + ((((kk * 4 + hi) * 16)) ^ ((row & 7) << 4));
        a[ri] = *(const bf16x8*)(s_buf + off);
      }
#pragma unroll
      for (int ci = 0; ci < 4; ++ci) {
        int n = w * 64 + ci * 16 + lo;
        b[ci] = *(const bf16x8*)(W2t + n * 256 + kk * 32 + hi * 8);
      }
#pragma unroll
      for (int ri = 0; ri < 4; ++ri)
#pragma unroll
        for (int ci = 0; ci < 4; ++ci)
          acc[ri][ci] = __builtin_amdgcn_mfma_f32_16x16x32_bf16(a[ri], b[ci], acc[ri][ci], 0, 0, 0);
    }
    float b2v[4];
#pragma unroll
    for (int ci = 0; ci < 4; ++ci) b2v[ci] = b2[w * 64 + ci * 16 + lo];
#pragma unroll
    for (int ri = 0; ri < 4; ++ri)
#pragma unroll
      for (int ci = 0; ci < 4; ++ci)
#pragma unroll
        for (int r = 0; r < 4; ++r) {
          int row = ri * 16 + hi * 4 + r;
          int col = w * 64 + ci * 16 + lo;
          out[(size_t)(base + row) * 256 + col] = acc[ri][ci][r] + b2v[ci];
        }
  }
}

extern "C" void kernel_launch(void* const* d_in, const int* in_sizes, int n_in,
                              void* d_out, int out_size, void* d_ws, size_t ws_size,
                              hipStream_t stream) {
  const float* rel    = (const float*)d_in[0];
  const float* node   = (const float*)d_in[1];
  const int*   eidx   = (const int*)d_in[2];
  const float* quest  = (const float*)d_in[3];
  const int*   ebat   = (const int*)d_in[4];
  const float* Wrel   = (const float*)d_in[5];
  const float* Wnode  = (const float*)d_in[6];
  const float* Wq     = (const float*)d_in[7];
  const float* W1     = (const float*)d_in[8];
  const float* bias1  = (const float*)d_in[9];
  const float* W2     = (const float*)d_in[10];
  const float* bias2  = (const float*)d_in[11];
  float* outp = (float*)d_out;
  bf16* ws = (bf16*)d_ws;

  const int E = in_sizes[4];  // 400000

  prep_weights<<<640, 256, 0, stream>>>(Wrel, Wnode, W1, W2, ws);
  prep_qg<<<64, 256, 0, stream>>>(quest, Wq, ws);
  fused_main<<<E / 64, 256, 0, stream>>>(
      rel, node, eidx + E, ebat,
      ws + WS_WREL_T, ws + WS_WNODE_T, ws + WS_W1T, ws + WS_W2T, ws + WS_QG,
      bias1, bias2, outp);
}

// Round 3
// 378.826 us; speedup vs baseline: 1.1643x; 1.1643x over previous
//
#include <hip/hip_runtime.h>

typedef __bf16 bf16;
typedef bf16 bf16x4 __attribute__((ext_vector_type(4)));
typedef bf16 bf16x8 __attribute__((ext_vector_type(8)));
typedef float f32x4 __attribute__((ext_vector_type(4)));

// ws element offsets (bf16 elements)
#define WS_WREL_T  0
#define WS_WNODE_T 16384
#define WS_W1T     32768
#define WS_W2T     98304
#define WS_QG      163840

// ---------- prep: transpose weights to B^T (N-major) bf16 ----------
__global__ void prep_weights(const float* __restrict__ Wrel,
                             const float* __restrict__ Wnode,
                             const float* __restrict__ W1,
                             const float* __restrict__ W2,
                             bf16* __restrict__ ws) {
  int id = blockIdx.x * 256 + threadIdx.x;
  if (id < 16384) {
    ws[WS_WREL_T + id] = (bf16)Wrel[(id & 127) * 128 + (id >> 7)];
  } else if (id < 32768) {
    int j = id - 16384;
    ws[WS_WNODE_T + j] = (bf16)Wnode[(j & 127) * 128 + (j >> 7)];
  } else if (id < 98304) {
    int j = id - 32768;
    ws[WS_W1T + j] = (bf16)W1[(j & 255) * 256 + (j >> 8)];
  } else if (id < 163840) {
    int j = id - 98304;
    ws[WS_W2T + j] = (bf16)W2[(j & 255) * 256 + (j >> 8)];
  }
}

// ---------- prep: qg[64][256] = sigmoid(question @ W_qgate), bf16 ----------
__global__ void prep_qg(const float* __restrict__ question,
                        const float* __restrict__ Wq,
                        bf16* __restrict__ ws) {
  int b = blockIdx.x, c = threadIdx.x;
  float s = 0.f;
#pragma unroll 8
  for (int k = 0; k < 128; ++k) s += question[b * 128 + k] * Wq[k * 256 + c];
  ws[WS_QG + b * 256 + c] = (bf16)(1.f / (1.f + expf(-s)));
}

__device__ __forceinline__ float gelu_erf(float x) {
  return 0.5f * x * (1.f + erff(x * 0.70710678118654752f));
}

// ---------- main fused kernel: 64 edges/block, 4 waves, 32KB union LDS ----------
__global__ __launch_bounds__(256, 3) void fused_main(
    const float* __restrict__ rel_tok,   // [E,128]
    const float* __restrict__ node_tok,  // [N,128]
    const int*   __restrict__ tail_idx,  // edge_index + E
    const int*   __restrict__ ebatch,    // [E]
    const bf16*  __restrict__ Wrel_t,    // [128][128] (B^T)
    const bf16*  __restrict__ Wnode_t,   // [128][128]
    const bf16*  __restrict__ W1t,       // [256][256]
    const bf16*  __restrict__ W2t,       // [256][256]
    const bf16*  __restrict__ qg,        // [64][256]
    const float* __restrict__ b1,
    const float* __restrict__ b2,
    float* __restrict__ out)             // [E,256]
{
  // One 32KB union buffer, three phase layouts:
  //  T : tokens  [2][64][128] bf16, byte off = h*16384 + row*256 + ((col*2)^((row&7)<<4))
  //  AK: act-key [64][256]    bf16, byte off = row*512 + ((col*2)^((row&7)<<4))
  //  H : hidden  same as AK
  __shared__ char s_buf[64 * 256 * 2];
  __shared__ int  s_eb[64];

  const int tid = threadIdx.x;
  const int w = tid >> 6;
  const int l = tid & 63;
  const int lo = l & 15;
  const int hi = l >> 4;
  const int base = blockIdx.x * 64;

  if (tid < 64) s_eb[tid] = ebatch[base + tid];

  // ---- stage tokens -> LDS bf16 (phase T) ----
  {
    const float4* g = (const float4*)rel_tok + (size_t)base * 32;
#pragma unroll
    for (int i = 0; i < 8; ++i) {
      int idx = tid + i * 256;          // over [64][32] float4
      int row = idx >> 5, c4 = idx & 31;
      float4 v = g[idx];
      bf16x4 b; b[0] = (bf16)v.x; b[1] = (bf16)v.y; b[2] = (bf16)v.z; b[3] = (bf16)v.w;
      int off = row * 256 + ((c4 * 8) ^ ((row & 7) << 4));
      *(bf16x4*)(s_buf + off) = b;
    }
#pragma unroll
    for (int i = 0; i < 8; ++i) {
      int idx = tid + i * 256;
      int row = idx >> 5, c4 = idx & 31;
      int tail = tail_idx[base + row];  // 32 lanes same addr: coalesces
      float4 v = ((const float4*)node_tok)[(size_t)tail * 32 + c4];
      bf16x4 b; b[0] = (bf16)v.x; b[1] = (bf16)v.y; b[2] = (bf16)v.z; b[3] = (bf16)v.w;
      int off = 16384 + row * 256 + ((c4 * 8) ^ ((row & 7) << 4));
      *(bf16x4*)(s_buf + off) = b;
    }
  }
  __syncthreads();   // (1) tokens + s_eb visible

  const f32x4 zero4 = {0.f, 0.f, 0.f, 0.f};

  // ---- stage 1: rel_key / node_key (K=128), gate -> packed regs ----
  bf16x4 pak[2][4][2];   // [h][ri][ci], 4 rows each = 64 bf16 = 32 VGPR
#pragma unroll
  for (int h = 0; h < 2; ++h) {
    const bf16* Wt = h ? Wnode_t : Wrel_t;
    f32x4 acc[4][2];
#pragma unroll
    for (int ri = 0; ri < 4; ++ri)
#pragma unroll
      for (int ci = 0; ci < 2; ++ci) acc[ri][ci] = zero4;

#pragma unroll
    for (int kk = 0; kk < 4; ++kk) {
      bf16x8 a[4], b[2];
#pragma unroll
      for (int ri = 0; ri < 4; ++ri) {
        int row = ri * 16 + lo;
        int off = h * 16384 + row * 256 + ((((kk * 4 + hi) * 16)) ^ ((row & 7) << 4));
        a[ri] = *(const bf16x8*)(s_buf + off);
      }
#pragma unroll
      for (int ci = 0; ci < 2; ++ci) {
        int n = w * 32 + ci * 16 + lo;
        b[ci] = *(const bf16x8*)(Wt + n * 128 + kk * 32 + hi * 8);
      }
#pragma unroll
      for (int ri = 0; ri < 4; ++ri)
#pragma unroll
        for (int ci = 0; ci < 2; ++ci)
          acc[ri][ci] = __builtin_amdgcn_mfma_f32_16x16x32_bf16(a[ri], b[ci], acc[ri][ci], 0, 0, 0);
    }
    // gate multiply into packed bf16 regs (no LDS write yet)
#pragma unroll
    for (int ri = 0; ri < 4; ++ri)
#pragma unroll
      for (int ci = 0; ci < 2; ++ci)
#pragma unroll
        for (int r = 0; r < 4; ++r) {
          int row = ri * 16 + hi * 4 + r;
          int col = h * 128 + w * 32 + ci * 16 + lo;
          float gv = (float)qg[s_eb[row] * 256 + col];
          pak[h][ri][ci][r] = (bf16)(acc[ri][ci][r] * gv);
        }
  }
  __syncthreads();   // (2) all waves done READING token phase

  // write action_key over the token buffer (phase AK)
#pragma unroll
  for (int h = 0; h < 2; ++h)
#pragma unroll
    for (int ri = 0; ri < 4; ++ri)
#pragma unroll
      for (int ci = 0; ci < 2; ++ci)
#pragma unroll
        for (int r = 0; r < 4; ++r) {
          int row = ri * 16 + hi * 4 + r;
          int col = h * 128 + w * 32 + ci * 16 + lo;
          int off = row * 512 + ((col * 2) ^ ((row & 7) << 4));
          *(bf16*)(s_buf + off) = pak[h][ri][ci][r];
        }
  __syncthreads();   // (3) AK visible

  // ---- stage 2: h = gelu(ak @ W1^T + b1) ----
  {
    f32x4 acc[4][4];
#pragma unroll
    for (int ri = 0; ri < 4; ++ri)
#pragma unroll
      for (int ci = 0; ci < 4; ++ci) acc[ri][ci] = zero4;

#pragma unroll
    for (int kk = 0; kk < 8; ++kk) {
      bf16x8 a[4], b[4];
#pragma unroll
      for (int ri = 0; ri < 4; ++ri) {
        int row = ri * 16 + lo;
        int off = row * 512 + ((((kk * 4 + hi) * 16)) ^ ((row & 7) << 4));
        a[ri] = *(const bf16x8*)(s_buf + off);
      }
#pragma unroll
      for (int ci = 0; ci < 4; ++ci) {
        int n = w * 64 + ci * 16 + lo;
        b[ci] = *(const bf16x8*)(W1t + n * 256 + kk * 32 + hi * 8);
      }
#pragma unroll
      for (int ri = 0; ri < 4; ++ri)
#pragma unroll
        for (int ci = 0; ci < 4; ++ci)
          acc[ri][ci] = __builtin_amdgcn_mfma_f32_16x16x32_bf16(a[ri], b[ci], acc[ri][ci], 0, 0, 0);
    }
    __syncthreads();   // (4) all waves done READING AK
    float b1v[4];
#pragma unroll
    for (int ci = 0; ci < 4; ++ci) b1v[ci] = b1[w * 64 + ci * 16 + lo];
#pragma unroll
    for (int ri = 0; ri < 4; ++ri)
#pragma unroll
      for (int ci = 0; ci < 4; ++ci)
#pragma unroll
        for (int r = 0; r < 4; ++r) {
          int row = ri * 16 + hi * 4 + r;
          int col = w * 64 + ci * 16 + lo;
          float v = gelu_erf(acc[ri][ci][r] + b1v[ci]);
          int off = row * 512 + ((col * 2) ^ ((row & 7) << 4));
          *(bf16*)(s_buf + off) = (bf16)v;
        }
  }
  __syncthreads();   // (5) H visible

  // ---- stage 3: out = h @ W2^T + b2 -> global fp32 ----
  {
    f32x4 acc[4][4];
#pragma unroll
    for (int ri = 0; ri < 4; ++ri)
#pragma unroll
      for (int ci = 0; ci < 4; ++ci) acc[ri][ci] = zero4;

#pragma unroll
    for (int kk = 0; kk < 8; ++kk) {
      bf16x8 a[4], b[4];
#pragma unroll
      for (int ri = 0; ri < 4; ++ri) {
        int row = ri * 16 + lo;
        int off = row * 512 + ((((kk * 4 + hi) * 16)) ^ ((row & 7) << 4));
        a[ri] = *(const bf16x8*)(s_buf + off);
      }
#pragma unroll
      for (int ci = 0; ci < 4; ++ci) {
        int n = w * 64 + ci * 16 + lo;
        b[ci] = *(const bf16x8*)(W2t + n * 256 + kk * 32 + hi * 8);
      }
#pragma unroll
      for (int ri = 0; ri < 4; ++ri)
#pragma unroll
        for (int ci = 0; ci < 4; ++ci)
          acc[ri][ci] = __builtin_amdgcn_mfma_f32_16x16x32_bf16(a[ri], b[ci], acc[ri][ci], 0, 0, 0);
    }
    float b2v[4];
#pragma unroll
    for (int ci = 0; ci < 4; ++ci) b2v[ci] = b2[w * 64 + ci * 16 + lo];
#pragma unroll
    for (int ri = 0; ri < 4; ++ri)
#pragma unroll
      for (int ci = 0; ci < 4; ++ci)
#pragma unroll
        for (int r = 0; r < 4; ++r) {
          int row = ri * 16 + hi * 4 + r;
          int col = w * 64 + ci * 16 + lo;
          out[(size_t)(base + row) * 256 + col] = acc[ri][ci][r] + b2v[ci];
        }
  }
}

extern "C" void kernel_launch(void* const* d_in, const int* in_sizes, int n_in,
                              void* d_out, int out_size, void* d_ws, size_t ws_size,
                              hipStream_t stream) {
  const float* rel    = (const float*)d_in[0];
  const float* node   = (const float*)d_in[1];
  const int*   eidx   = (const int*)d_in[2];
  const float* quest  = (const float*)d_in[3];
  const int*   ebat   = (const int*)d_in[4];
  const float* Wrel   = (const float*)d_in[5];
  const float* Wnode  = (const float*)d_in[6];
  const float* Wq     = (const float*)d_in[7];
  const float* W1     = (const float*)d_in[8];
  const float* bias1  = (const float*)d_in[9];
  const float* W2     = (const float*)d_in[10];
  const float* bias2  = (const float*)d_in[11];
  float* outp = (float*)d_out;
  bf16* ws = (bf16*)d_ws;

  const int E = in_sizes[4];  // 400000

  prep_weights<<<640, 256, 0, stream>>>(Wrel, Wnode, W1, W2, ws);
  prep_qg<<<64, 256, 0, stream>>>(quest, Wq, ws);
  fused_main<<<E / 64, 256, 0, stream>>>(
      rel, node, eidx + E, ebat,
      ws + WS_WREL_T, ws + WS_WNODE_T, ws + WS_W1T, ws + WS_W2T, ws + WS_QG,
      bias1, bias2, outp);
}